// Round 2
// baseline (268.583 us; speedup 1.0000x reference)
//
#include <hip/hip_runtime.h>
#include <hip/hip_bf16.h>
#include <math.h>

#define LVL 10
#define TBL 65536u
#define KS 4
#define HIDN 64
#define OUTD 29
#define DIN 40   // L*F, flat index = f*LVL + l

struct ResArr { float r[LVL]; };

__device__ __forceinline__ float selu_f(float v) {
    const float sc = 1.0507009873554805f;           // jax.nn.selu scale
    const float sa = 1.7580993408473766f;           // scale*alpha
    return v > 0.f ? sc * v : sa * expm1f(v);
}

__global__ __launch_bounds__(256) void ingp_fused(
    const float* __restrict__ xg, const float* __restrict__ crg,
    const float* __restrict__ epsg, const float* __restrict__ table,
    const float* __restrict__ W1, const float* __restrict__ b1,
    const float* __restrict__ W2, const float* __restrict__ b2,
    const float* __restrict__ W3, const float* __restrict__ b3,
    float* __restrict__ out, int npts, ResArr res)
{
    const int p = blockIdx.x * blockDim.x + threadIdx.x;
    if (p >= npts) return;

    const float cvx = fmaf(4.f, xg[p*3+0], -2.f);
    const float cvy = fmaf(4.f, xg[p*3+1], -2.f);
    const float cvz = fmaf(4.f, xg[p*3+2], -2.f);
    const float crv = crg[p];
    const float tc  = 0.3f * crv;   // TRUNC * cr

    float hacc[DIN];
#pragma unroll
    for (int i = 0; i < DIN; ++i) hacc[i] = 0.f;

    for (int k = 0; k < KS; ++k) {
        const float* ep = epsg + ((size_t)p * KS + k) * 3;
        // s_x = clip(cv + eps*tc, -1, 1)/4 + 0.5
        const float sx = fmaf(fminf(fmaxf(fmaf(ep[0], tc, cvx), -1.f), 1.f), 0.25f, 0.5f);
        const float sy = fmaf(fminf(fmaxf(fmaf(ep[1], tc, cvy), -1.f), 1.f), 0.25f, 0.5f);
        const float sz = fmaf(fminf(fmaxf(fmaf(ep[2], tc, cvz), -1.f), 1.f), 0.25f, 0.5f);

#pragma unroll
        for (int l = 0; l < LVL; ++l) {
            const float rs = res.r[l];
            const float xs = sx * rs, ys = sy * rs, zs = sz * rs;
            const float fx = floorf(xs), fy = floorf(ys), fz = floorf(zs);
            const float frx = xs - fx, fry = ys - fy, frz = zs - fz;
            const unsigned cx = (unsigned)fx, cy = (unsigned)fy, cz = (unsigned)fz;
            const unsigned hx0 = cx,                 hx1 = cx + 1u;
            const unsigned hy0 = cy * 2654435761u,   hy1 = hy0 + 2654435761u;
            const unsigned hz0 = cz * 805459861u,    hz1 = hz0 + 805459861u;
            const float wx1 = frx, wx0 = 1.f - frx;
            const float wy1 = fry, wy0 = 1.f - fry;
            const float wz1 = frz, wz0 = 1.f - frz;
            const float4* tl = (const float4*)table + (size_t)l * TBL;
            float4 a = make_float4(0.f, 0.f, 0.f, 0.f);
#define CORNER(HX,HY,HZ,WX,WY,WZ) do { \
                unsigned id = ((HX) ^ (HY) ^ (HZ)) & (TBL - 1u); \
                float4 f = tl[id]; \
                float w = (WX) * (WY) * (WZ); \
                a.x = fmaf(w, f.x, a.x); a.y = fmaf(w, f.y, a.y); \
                a.z = fmaf(w, f.z, a.z); a.w = fmaf(w, f.w, a.w); \
            } while (0)
            CORNER(hx0, hy0, hz0, wx0, wy0, wz0);
            CORNER(hx0, hy0, hz1, wx0, wy0, wz1);
            CORNER(hx0, hy1, hz0, wx0, wy1, wz0);
            CORNER(hx0, hy1, hz1, wx0, wy1, wz1);
            CORNER(hx1, hy0, hz0, wx1, wy0, wz0);
            CORNER(hx1, hy0, hz1, wx1, wy0, wz1);
            CORNER(hx1, hy1, hz0, wx1, wy1, wz0);
            CORNER(hx1, hy1, hz1, wx1, wy1, wz1);
#undef CORNER
            hacc[0*LVL + l] += a.x;
            hacc[1*LVL + l] += a.y;
            hacc[2*LVL + l] += a.z;
            hacc[3*LVL + l] += a.w;
        }
    }

    // window * mean over K   (cr identical across the K samples of a point)
    float h[DIN];
#pragma unroll
    for (int l = 0; l < LVL; ++l) {
        const float den = fmaxf(8.f * (float)l * crv, 1e-12f);  // PLS*4*l*cr
        const float win = erff(rsqrtf(den));
        const float s = 0.25f * win;
        h[0*LVL + l] = hacc[0*LVL + l] * s;
        h[1*LVL + l] = hacc[1*LVL + l] * s;
        h[2*LVL + l] = hacc[2*LVL + l] * s;
        h[3*LVL + l] = hacc[3*LVL + l] * s;
    }

    // ---- MLP (weights are wave-uniform -> scalar loads; all indices static)
    float h1[HIDN];
#pragma unroll
    for (int j = 0; j < HIDN; ++j) {
        float acc = b1[j];
#pragma unroll
        for (int i = 0; i < DIN; ++i) acc = fmaf(h[i], W1[j*DIN + i], acc);
        h1[j] = selu_f(acc);
    }
    float h2[HIDN];
#pragma unroll
    for (int j = 0; j < HIDN; ++j) {
        float acc = b2[j];
#pragma unroll
        for (int i = 0; i < HIDN; ++i) acc = fmaf(h1[i], W2[j*HIDN + i], acc);
        h2[j] = selu_f(acc);
    }
    float o[OUTD];
#pragma unroll
    for (int j = 0; j < OUTD; ++j) {
        float acc = b3[j];
#pragma unroll
        for (int i = 0; i < HIDN; ++i) acc = fmaf(h2[i], W3[j*HIDN + i], acc);
        o[j] = acc;
    }

    // ---- outputs (fp32): density(B), rgb(3B), grd(9B), sh(16B), concatenated
    float* dns  = out;
    float* rgbp = out + (size_t)npts;
    float* grdp = out + (size_t)npts * 4;
    float* shp  = out + (size_t)npts * 13;

    dns[p] = expf(o[0] - 4.f);  // DOFF = -4

    float rr[3];
#pragma unroll
    for (int c = 0; c < 3; ++c) {
        rr[c] = o[1 + c] + 0.5f;
        rgbp[(size_t)p*3 + c] = rr[c];
    }
#pragma unroll
    for (int r = 0; r < 3; ++r)
#pragma unroll
        for (int c = 0; c < 3; ++c)
            grdp[(size_t)p*9 + r*3 + c] = rr[r] * tanhf(o[4 + r*3 + c]);
#pragma unroll
    for (int s = 0; s < 16; ++s)
        shp[(size_t)p*16 + s] = o[13 + s];
}

extern "C" void kernel_launch(void* const* d_in, const int* in_sizes, int n_in,
                              void* d_out, int out_size, void* d_ws, size_t ws_size,
                              hipStream_t stream) {
    const float* x     = (const float*)d_in[0];
    const float* cr    = (const float*)d_in[1];
    const float* eps   = (const float*)d_in[2];
    const float* table = (const float*)d_in[3];
    const float* W1    = (const float*)d_in[4];
    const float* b1    = (const float*)d_in[5];
    const float* W2    = (const float*)d_in[6];
    const float* b2    = (const float*)d_in[7];
    const float* W3    = (const float*)d_in[8];
    const float* b3    = (const float*)d_in[9];
    float* out = (float*)d_out;

    const int npts = in_sizes[0] / 3;

    // Replicate numpy: RES = floor(16 * b^l), b = exp(log(2^10)/9), in double.
    ResArr res;
    const double bg = exp(log(pow(2.0, 10.0)) / 9.0);
    for (int l = 0; l < LVL; ++l) res.r[l] = (float)floor(16.0 * pow(bg, (double)l));

    const int block = 256;
    const int grid = (npts + block - 1) / block;
    hipLaunchKernelGGL(ingp_fused, dim3(grid), dim3(block), 0, stream,
                       x, cr, eps, table, W1, b1, W2, b2, W3, b3, out, npts, res);
}

// Round 3
// 249.150 us; speedup vs baseline: 1.0780x; 1.0780x over previous
//
#include <hip/hip_runtime.h>
#include <hip/hip_bf16.h>
#include <math.h>

#define LVL 10
#define TBL 65536u
#define KS 4
#define HIDN 64
#define OUTD 29
#define DIN 40            // L*F, flat col = f*LVL + l
#define PTS 64            // points per block
#define STR 65            // LDS row stride (pad: 65 -> bank (p+i)%32, conflict-free)

struct ResArr { float r[LVL]; };

__device__ __forceinline__ float selu_f(float v) {
    const float sc = 1.0507009873554805f;
    const float sa = 1.7580993408473766f;
    return v > 0.f ? sc * v : sa * expm1f(v);
}

__global__ __launch_bounds__(256, 4) void ingp_fused(
    const float* __restrict__ xg, const float* __restrict__ crg,
    const float* __restrict__ epsg, const float* __restrict__ table,
    const float* __restrict__ W1, const float* __restrict__ b1,
    const float* __restrict__ W2, const float* __restrict__ b2,
    const float* __restrict__ W3, const float* __restrict__ b3,
    float* __restrict__ out, int npts, ResArr res)
{
    __shared__ float A[PTS][STR];   // h (40 cols) -> later h2 (64 cols)
    __shared__ float Bb[PTS][STR];  // h1 (64 cols) -> later raw o (29 cols)

    const int t    = threadIdx.x;
    const int lane = t & 63;        // point within block
    const int wv   = t >> 6;        // wave = k sample / row chunk
    const int pg   = blockIdx.x * PTS + lane;
    const bool ok  = pg < npts;

    // zero accumulator buffer
    for (int i = t; i < PTS * STR; i += 256) ((float*)A)[i] = 0.f;
    __syncthreads();

    const float crv = ok ? crg[pg] : 1.0f;

    // ---- phase 1: hash-grid gather, one (point, k) per thread ----
    if (ok) {
        const float cvx = fmaf(4.f, xg[pg*3+0], -2.f);
        const float cvy = fmaf(4.f, xg[pg*3+1], -2.f);
        const float cvz = fmaf(4.f, xg[pg*3+2], -2.f);
        const float tc  = 0.3f * crv;
        const float* ep = epsg + ((size_t)pg * KS + wv) * 3;
        const float sx = fmaf(fminf(fmaxf(fmaf(ep[0], tc, cvx), -1.f), 1.f), 0.25f, 0.5f);
        const float sy = fmaf(fminf(fmaxf(fmaf(ep[1], tc, cvy), -1.f), 1.f), 0.25f, 0.5f);
        const float sz = fmaf(fminf(fmaxf(fmaf(ep[2], tc, cvz), -1.f), 1.f), 0.25f, 0.5f);

#pragma unroll
        for (int l = 0; l < LVL; ++l) {
            const float rs = res.r[l];
            const float xs = sx * rs, ys = sy * rs, zs = sz * rs;
            const float fx = floorf(xs), fy = floorf(ys), fz = floorf(zs);
            const float frx = xs - fx, fry = ys - fy, frz = zs - fz;
            const unsigned cx = (unsigned)fx, cy = (unsigned)fy, cz = (unsigned)fz;
            const unsigned hx0 = cx,               hx1 = cx + 1u;
            const unsigned hy0 = cy * 2654435761u, hy1 = hy0 + 2654435761u;
            const unsigned hz0 = cz * 805459861u,  hz1 = hz0 + 805459861u;
            const float wx1 = frx, wx0 = 1.f - frx;
            const float wy1 = fry, wy0 = 1.f - fry;
            const float wz1 = frz, wz0 = 1.f - frz;
            const float4* tl = (const float4*)table + (size_t)l * TBL;
            float4 a = make_float4(0.f, 0.f, 0.f, 0.f);
#define CORNER(HX,HY,HZ,WX,WY,WZ) do { \
                unsigned id = ((HX) ^ (HY) ^ (HZ)) & (TBL - 1u); \
                float4 f = tl[id]; \
                float w = (WX) * (WY) * (WZ); \
                a.x = fmaf(w, f.x, a.x); a.y = fmaf(w, f.y, a.y); \
                a.z = fmaf(w, f.z, a.z); a.w = fmaf(w, f.w, a.w); \
            } while (0)
            CORNER(hx0, hy0, hz0, wx0, wy0, wz0);
            CORNER(hx0, hy0, hz1, wx0, wy0, wz1);
            CORNER(hx0, hy1, hz0, wx0, wy1, wz0);
            CORNER(hx0, hy1, hz1, wx0, wy1, wz1);
            CORNER(hx1, hy0, hz0, wx1, wy0, wz0);
            CORNER(hx1, hy0, hz1, wx1, wy0, wz1);
            CORNER(hx1, hy1, hz0, wx1, wy1, wz0);
            CORNER(hx1, hy1, hz1, wx1, wy1, wz1);
#undef CORNER
            atomicAdd(&A[lane][0*LVL + l], a.x);
            atomicAdd(&A[lane][1*LVL + l], a.y);
            atomicAdd(&A[lane][2*LVL + l], a.z);
            atomicAdd(&A[lane][3*LVL + l], a.w);
        }
    }
    __syncthreads();

    // ---- phase 2: window * mean(K);  wave wv scales feature f = wv ----
    {
#pragma unroll
        for (int l = 0; l < LVL; ++l) {
            const float den = fmaxf(8.f * (float)l * crv, 1e-12f);
            const float win = erff(rsqrtf(den));
            A[lane][wv*LVL + l] *= 0.25f * win;
        }
    }
    __syncthreads();

    const int wu = __builtin_amdgcn_readfirstlane(wv);  // force wave-uniform -> scalar weight loads

    // ---- phase 3: layer 1 (40 -> 64), wave wu computes rows [wu*16, wu*16+16) ----
    {
        float acc[16];
#pragma unroll
        for (int jj = 0; jj < 16; ++jj) acc[jj] = b1[wu*16 + jj];
#pragma unroll
        for (int i = 0; i < DIN; ++i) {
            const float hv = A[lane][i];
#pragma unroll
            for (int jj = 0; jj < 16; ++jj)
                acc[jj] = fmaf(hv, W1[(wu*16 + jj)*DIN + i], acc[jj]);
        }
#pragma unroll
        for (int jj = 0; jj < 16; ++jj) Bb[lane][wu*16 + jj] = selu_f(acc[jj]);
    }
    __syncthreads();

    // ---- phase 4: layer 2 (64 -> 64) ----
    {
        float acc[16];
#pragma unroll
        for (int jj = 0; jj < 16; ++jj) acc[jj] = b2[wu*16 + jj];
#pragma unroll
        for (int i = 0; i < HIDN; ++i) {
            const float hv = Bb[lane][i];
#pragma unroll
            for (int jj = 0; jj < 16; ++jj)
                acc[jj] = fmaf(hv, W2[(wu*16 + jj)*HIDN + i], acc[jj]);
        }
#pragma unroll
        for (int jj = 0; jj < 16; ++jj) A[lane][wu*16 + jj] = selu_f(acc[jj]);
    }
    __syncthreads();

    // ---- phase 5: layer 3 (64 -> 29); waves own rows 8/8/8/5, raw o -> Bb ----
    {
        const int base = wu * 8;
        const int cnt  = (wu == 3) ? 5 : 8;
        float acc[8];
#pragma unroll
        for (int jj = 0; jj < 8; ++jj) acc[jj] = (jj < cnt) ? b3[base + jj] : 0.f;
#pragma unroll
        for (int i = 0; i < HIDN; ++i) {
            const float hv = A[lane][i];
#pragma unroll
            for (int jj = 0; jj < 8; ++jj)
                if (jj < cnt) acc[jj] = fmaf(hv, W3[(base + jj)*HIDN + i], acc[jj]);
        }
#pragma unroll
        for (int jj = 0; jj < 8; ++jj)
            if (jj < cnt) Bb[lane][base + jj] = acc[jj];
    }
    __syncthreads();

    // ---- phase 6: epilogue by wave 0 ----
    if (wv == 0 && ok) {
        float o[OUTD];
#pragma unroll
        for (int j = 0; j < OUTD; ++j) o[j] = Bb[lane][j];

        float* dns  = out;
        float* rgbp = out + (size_t)npts;
        float* grdp = out + (size_t)npts * 4;
        float* shp  = out + (size_t)npts * 13;

        dns[pg] = expf(o[0] - 4.f);
        float rr[3];
#pragma unroll
        for (int c = 0; c < 3; ++c) {
            rr[c] = o[1 + c] + 0.5f;
            rgbp[(size_t)pg*3 + c] = rr[c];
        }
#pragma unroll
        for (int r = 0; r < 3; ++r)
#pragma unroll
            for (int c = 0; c < 3; ++c)
                grdp[(size_t)pg*9 + r*3 + c] = rr[r] * tanhf(o[4 + r*3 + c]);
#pragma unroll
        for (int s = 0; s < 16; ++s)
            shp[(size_t)pg*16 + s] = o[13 + s];
    }
}

extern "C" void kernel_launch(void* const* d_in, const int* in_sizes, int n_in,
                              void* d_out, int out_size, void* d_ws, size_t ws_size,
                              hipStream_t stream) {
    const float* x     = (const float*)d_in[0];
    const float* cr    = (const float*)d_in[1];
    const float* eps   = (const float*)d_in[2];
    const float* table = (const float*)d_in[3];
    const float* W1    = (const float*)d_in[4];
    const float* b1    = (const float*)d_in[5];
    const float* W2    = (const float*)d_in[6];
    const float* b2    = (const float*)d_in[7];
    const float* W3    = (const float*)d_in[8];
    const float* b3    = (const float*)d_in[9];
    float* out = (float*)d_out;

    const int npts = in_sizes[0] / 3;

    ResArr res;
    const double bg = exp(log(pow(2.0, 10.0)) / 9.0);
    for (int l = 0; l < LVL; ++l) res.r[l] = (float)floor(16.0 * pow(bg, (double)l));

    const int grid = (npts + PTS - 1) / PTS;
    hipLaunchKernelGGL(ingp_fused, dim3(grid), dim3(256), 0, stream,
                       x, cr, eps, table, W1, b1, W2, b2, W3, b3, out, npts, res);
}